// Round 8
// baseline (165.303 us; speedup 1.0000x reference)
//
#include <hip/hip_runtime.h>
#include <math.h>

#define S_N 2048
#define X_N 2048
#define G_N 2
#define F_N 3072

#define TM 128
#define TN 128
#define BK 64
#define ITERS (F_N / BK)  // 48
#define NB (X_N / TN)     // 16 col-blocks

typedef __bf16 bf16;
typedef __bf16 bf16x4 __attribute__((ext_vector_type(4)));
typedef __bf16 bf16x8 __attribute__((ext_vector_type(8)));
typedef float f32x4 __attribute__((ext_vector_type(4)));
typedef int i32x4 __attribute__((ext_vector_type(4)));

// lgkm-only drain + barrier; memory clobber pins DS ordering, vmcnt stays in flight
#define LGKM_BARRIER() asm volatile("s_waitcnt lgkmcnt(0)\n\ts_barrier" ::: "memory")

// ---------------- P0: u = s/std_g (bf16, rcp inline) + A[g,s]=||u||^2 ; x->v,C
__global__ void k_prep(const float* __restrict__ samples, const float* __restrict__ xin,
                       const float* __restrict__ stdv,
                       bf16* __restrict__ U, bf16* __restrict__ V,
                       float* __restrict__ A, float* __restrict__ C) {
  int r = blockIdx.x;
  int t = threadIdx.x;
  bool isS = (r < S_N);
  const float* src = isS ? (samples + (size_t)r * F_N) : (xin + (size_t)(r - S_N) * F_N);
  float4 row[3];
#pragma unroll
  for (int j = 0; j < 3; ++j) row[j] = ((const float4*)src)[t + j * 256];

  __shared__ float red[4];
  int w = t >> 6, l = t & 63;

  for (int g = 0; g < G_N; ++g) {
    const float4* sd = (const float4*)(stdv + (size_t)g * F_N);
    bf16* dst = isS ? (U + ((size_t)g * S_N + r) * F_N)
                    : (V + ((size_t)g * X_N + (r - S_N)) * F_N);
    float acc = 0.f;
#pragma unroll
    for (int j = 0; j < 3; ++j) {
      float4 d = sd[t + j * 256];
      // v_rcp_f32: ~1ulp rel err, negligible vs bf16 rounding
      float u0 = row[j].x * __builtin_amdgcn_rcpf(d.x);
      float u1 = row[j].y * __builtin_amdgcn_rcpf(d.y);
      float u2 = row[j].z * __builtin_amdgcn_rcpf(d.z);
      float u3 = row[j].w * __builtin_amdgcn_rcpf(d.w);
      bf16x4 b;
      b[0] = (bf16)u0; b[1] = (bf16)u1; b[2] = (bf16)u2; b[3] = (bf16)u3;
      float f0 = (float)b[0], f1 = (float)b[1], f2 = (float)b[2], f3 = (float)b[3];
      acc += f0 * f0 + f1 * f1 + f2 * f2 + f3 * f3;
      ((bf16x4*)dst)[t + j * 256] = b;
    }
    for (int o = 32; o; o >>= 1) acc += __shfl_xor(acc, o);
    __syncthreads();
    if (l == 0) red[w] = acc;
    __syncthreads();
    if (t == 0) {
      float tot = red[0] + red[1] + red[2] + red[3];
      if (isS) A[(size_t)g * S_N + r] = tot;
      else     C[(size_t)g * X_N + (r - S_N)] = tot;
    }
  }
}

// ---------------- P1: GEMM + fused row-wise LSE partials ----
// K-loop identical to R7 (BK=64, register pipeline, lgkm-only barrier).
// Epilogue: per block, per row: m = max over 128 cols of logit, s = sum exp;
// logit = uv - 0.5(A+C)  (const_g deferred to k_final since lse(v+c)=lse(v)+c).
// Writes pm/ps[G][NB][S_N] (512 KB total) instead of 33.6 MB logits.
__global__ __launch_bounds__(256, 2) void k_gemm(const bf16* __restrict__ U, const bf16* __restrict__ V,
                                                 const float* __restrict__ A, const float* __restrict__ C,
                                                 float* __restrict__ pm, float* __restrict__ ps) {
  __shared__ i32x4 ldsA[2][TM * BK / 8];  // 1024 slots x 16B per buf
  __shared__ i32x4 ldsB[2][TN * BK / 8];
  __shared__ float lms[2][TM];
  __shared__ float lss[2][TM];

  int t = threadIdx.x;
  int g = blockIdx.z;
  int bm = blockIdx.y * TM;
  int bn = blockIdx.x * TN;

  const bf16* Ub = U + ((size_t)g * S_N + bm) * F_N;
  const bf16* Vb = V + ((size_t)g * X_N + bn) * F_N;

  int wave = t >> 6, lane = t & 63;
  int wm = wave & 1, wn = wave >> 1;   // 2x2 waves, 64x64 each
  int r = lane & 15, q = lane >> 4;
  int fr = (r >> 1) & 7;               // 3-bit read swizzle
  int ck0 = q ^ fr;                    // slot chunk for ks=0
  int ck1 = (4 | q) ^ fr;              // slot chunk for ks=1

  int row0 = t >> 3;
  int gcc = (t & 7) ^ ((t >> 4) & 7);
  const bf16* gA[4];
  const bf16* gB[4];
#pragma unroll
  for (int j = 0; j < 4; ++j) {
    gA[j] = Ub + (size_t)(row0 + j * 32) * F_N + gcc * 8;
    gB[j] = Vb + (size_t)(row0 + j * 32) * F_N + gcc * 8;
  }

  f32x4 acc[4][4] = {};
  int abase = (wm * 64 + r) * 8;
  int bbase = (wn * 64 + r) * 8;

  i32x4 sA0[4], sB0[4], sA1[4], sB1[4];

#pragma unroll
  for (int j = 0; j < 4; ++j) {
    sA0[j] = *(const i32x4*)(gA[j]);
    sB0[j] = *(const i32x4*)(gB[j]);
  }
#pragma unroll
  for (int j = 0; j < 4; ++j) {
    sA1[j] = *(const i32x4*)(gA[j] + BK);
    sB1[j] = *(const i32x4*)(gB[j] + BK);
  }
#pragma unroll
  for (int j = 0; j < 4; ++j) {
    ldsA[0][t + j * 256] = sA0[j];
    ldsB[0][t + j * 256] = sB0[j];
  }
  LGKM_BARRIER();

  for (int it = 0; it < ITERS; it += 2) {
    {
      int k2 = it + 2;
      int pk = (k2 < ITERS ? k2 : 0) * BK;
#pragma unroll
      for (int j = 0; j < 4; ++j) {
        sA0[j] = *(const i32x4*)(gA[j] + pk);
        sB0[j] = *(const i32x4*)(gB[j] + pk);
      }
#pragma unroll
      for (int ks = 0; ks < 2; ++ks) {
        int ck = ks ? ck1 : ck0;
        bf16x8 af[4], bfr[4];
#pragma unroll
        for (int mi = 0; mi < 4; ++mi)
          af[mi] = __builtin_bit_cast(bf16x8, ldsA[0][abase + mi * 128 + ck]);
#pragma unroll
        for (int ni = 0; ni < 4; ++ni)
          bfr[ni] = __builtin_bit_cast(bf16x8, ldsB[0][bbase + ni * 128 + ck]);
#pragma unroll
        for (int mi = 0; mi < 4; ++mi)
#pragma unroll
          for (int ni = 0; ni < 4; ++ni)
            acc[mi][ni] = __builtin_amdgcn_mfma_f32_16x16x32_bf16(af[mi], bfr[ni], acc[mi][ni], 0, 0, 0);
      }
#pragma unroll
      for (int j = 0; j < 4; ++j) {
        ldsA[1][t + j * 256] = sA1[j];
        ldsB[1][t + j * 256] = sB1[j];
      }
      LGKM_BARRIER();
    }
    {
      int k3 = it + 3;
      int pk = (k3 < ITERS ? k3 : 0) * BK;
#pragma unroll
      for (int j = 0; j < 4; ++j) {
        sA1[j] = *(const i32x4*)(gA[j] + pk);
        sB1[j] = *(const i32x4*)(gB[j] + pk);
      }
#pragma unroll
      for (int ks = 0; ks < 2; ++ks) {
        int ck = ks ? ck1 : ck0;
        bf16x8 af[4], bfr[4];
#pragma unroll
        for (int mi = 0; mi < 4; ++mi)
          af[mi] = __builtin_bit_cast(bf16x8, ldsA[1][abase + mi * 128 + ck]);
#pragma unroll
        for (int ni = 0; ni < 4; ++ni)
          bfr[ni] = __builtin_bit_cast(bf16x8, ldsB[1][bbase + ni * 128 + ck]);
#pragma unroll
        for (int mi = 0; mi < 4; ++mi)
#pragma unroll
          for (int ni = 0; ni < 4; ++ni)
            acc[mi][ni] = __builtin_amdgcn_mfma_f32_16x16x32_bf16(af[mi], bfr[ni], acc[mi][ni], 0, 0, 0);
      }
#pragma unroll
      for (int j = 0; j < 4; ++j) {
        ldsA[0][t + j * 256] = sA0[j];
        ldsB[0][t + j * 256] = sB0[j];
      }
      LGKM_BARRIER();
    }
  }

  // ---- fused epilogue: per-row (max, sumexp) over this block's 128 cols ----
  // C/D layout: col = ni*16 + r, row = mi*16 + q*4 + i (within wave tile).
  const float* Ap = A + (size_t)g * S_N + bm + wm * 64;
  const float* Cp = C + (size_t)g * X_N + bn + wn * 64;
  float cv[4];
#pragma unroll
  for (int ni = 0; ni < 4; ++ni) cv[ni] = Cp[ni * 16 + r];

  float mloc[4][4], sloc[4][4];
#pragma unroll
  for (int mi = 0; mi < 4; ++mi) {
#pragma unroll
    for (int i = 0; i < 4; ++i) {
      float av = Ap[mi * 16 + q * 4 + i];
      float l0 = acc[mi][0][i] - 0.5f * (av + cv[0]);
      float l1 = acc[mi][1][i] - 0.5f * (av + cv[1]);
      float l2 = acc[mi][2][i] - 0.5f * (av + cv[2]);
      float l3 = acc[mi][3][i] - 0.5f * (av + cv[3]);
      float m = fmaxf(fmaxf(l0, l1), fmaxf(l2, l3));
      // reduce over the 16-lane r-group (lanes q*16 + r)
      m = fmaxf(m, __shfl_xor(m, 1));
      m = fmaxf(m, __shfl_xor(m, 2));
      m = fmaxf(m, __shfl_xor(m, 4));
      m = fmaxf(m, __shfl_xor(m, 8));
      float s = expf(l0 - m) + expf(l1 - m) + expf(l2 - m) + expf(l3 - m);
      s += __shfl_xor(s, 1);
      s += __shfl_xor(s, 2);
      s += __shfl_xor(s, 4);
      s += __shfl_xor(s, 8);
      mloc[mi][i] = m;
      sloc[mi][i] = s;
    }
  }
  if (r == 0) {
#pragma unroll
    for (int mi = 0; mi < 4; ++mi)
#pragma unroll
      for (int i = 0; i < 4; ++i) {
        int rowl = wm * 64 + mi * 16 + q * 4 + i;
        lms[wn][rowl] = mloc[mi][i];
        lss[wn][rowl] = sloc[mi][i];
      }
  }
  __syncthreads();
  if (t < TM) {
    float m0 = lms[0][t], m1 = lms[1][t];
    float s0 = lss[0][t], s1 = lss[1][t];
    float M = fmaxf(m0, m1);
    float S = s0 * expf(m0 - M) + s1 * expf(m1 - M);
    size_t idx = ((size_t)g * NB + blockIdx.x) * S_N + bm + t;
    pm[idx] = M;
    ps[idx] = S;
  }
}

// ---------------- P2: out[s] = combine partials over (g, colblock) + const_g
__global__ void k_final(const float* __restrict__ stdv,
                        const float* __restrict__ pm, const float* __restrict__ ps,
                        float* __restrict__ out) {
  int t = threadIdx.x;
  int s = blockIdx.x * 256 + t;

  // const_g computed per block (redundant, cheap): -0.5*F*log(2pi) - sum log std
  __shared__ float cgs[G_N];
  __shared__ float red[4];
  for (int g = 0; g < G_N; ++g) {
    float a = 0.f;
    for (int f = t; f < F_N; f += 256) a += logf(stdv[g * F_N + f]);
    for (int o = 32; o; o >>= 1) a += __shfl_xor(a, o);
    __syncthreads();
    if ((t & 63) == 0) red[t >> 6] = a;
    __syncthreads();
    if (t == 0) cgs[g] = -0.5f * (float)F_N * 1.8378770664093453f
                         - (red[0] + red[1] + red[2] + red[3]);
    __syncthreads();
  }
  float cg[G_N];
#pragma unroll
  for (int g = 0; g < G_N; ++g) cg[g] = cgs[g];

  float mv[G_N][NB];
  float M = -INFINITY;
#pragma unroll
  for (int g = 0; g < G_N; ++g)
#pragma unroll
    for (int cb = 0; cb < NB; ++cb) {
      float m = pm[((size_t)g * NB + cb) * S_N + s] + cg[g];
      mv[g][cb] = m;
      M = fmaxf(M, m);
    }
  float T = 0.f;
#pragma unroll
  for (int g = 0; g < G_N; ++g)
#pragma unroll
    for (int cb = 0; cb < NB; ++cb)
      T += ps[((size_t)g * NB + cb) * S_N + s] * expf(mv[g][cb] - M);
  out[s] = M + logf(T) - 8.317766166719343f;  // log(4096)
}

extern "C" void kernel_launch(void* const* d_in, const int* in_sizes, int n_in,
                              void* d_out, int out_size, void* d_ws, size_t ws_size,
                              hipStream_t stream) {
  const float* samples = (const float*)d_in[0];  // [S, F] fp32
  const float* xin     = (const float*)d_in[1];  // [X, F] fp32
  const float* stdv    = (const float*)d_in[2];  // [G, F] fp32
  float* out = (float*)d_out;                    // [S] fp32

  char* ws = (char*)d_ws;
  size_t off = 0;
  bf16* U = (bf16*)(ws + off);     off += (size_t)G_N * S_N * F_N * 2;  // 25.2 MB
  bf16* V = (bf16*)(ws + off);     off += (size_t)G_N * X_N * F_N * 2;  // 25.2 MB
  float* A = (float*)(ws + off);   off += (size_t)G_N * S_N * 4;
  float* C = (float*)(ws + off);   off += (size_t)G_N * X_N * 4;
  float* pm = (float*)(ws + off);  off += (size_t)G_N * NB * S_N * 4;   // 256 KB
  float* ps = (float*)(ws + off);  off += (size_t)G_N * NB * S_N * 4;   // 256 KB

  k_prep<<<dim3(S_N + X_N), dim3(256), 0, stream>>>(samples, xin, stdv, U, V, A, C);
  k_gemm<<<dim3(X_N / TN, S_N / TM, G_N), dim3(256), 0, stream>>>(U, V, A, C, pm, ps);
  k_final<<<dim3(S_N / 256), dim3(256), 0, stream>>>(stdv, pm, ps, out);
}